// Round 3
// baseline (3642.297 us; speedup 1.0000x reference)
//
#include <hip/hip_runtime.h>
#include <stdint.h>

#define NB 32
#define CC 256
#define HH 56
#define WW 56
#define PP (HH*WW)          // 3136
#define NPIX (NB*PP)        // 100352
#define W32 8               // 256 channels / 32 bits
#define KEPS 1e-5f

// ---------------- BN stats: per-(n,c) plane partial sums -> atomics ----------------
__global__ void k_stats(const float* __restrict__ x, float* __restrict__ ssum, float* __restrict__ ssq) {
    int plane = blockIdx.x;               // n*CC + c
    int c = plane & (CC - 1);
    const float* xp = x + (size_t)plane * PP;
    float s = 0.f, q = 0.f;
    for (int i = threadIdx.x; i < PP; i += blockDim.x) {
        float v = xp[i]; s += v; q = fmaf(v, v, q);
    }
#pragma unroll
    for (int off = 32; off; off >>= 1) { s += __shfl_down(s, off); q += __shfl_down(q, off); }
    __shared__ float ls[4], lq[4];
    int wv = threadIdx.x >> 6, ln = threadIdx.x & 63;
    if (ln == 0) { ls[wv] = s; lq[wv] = q; }
    __syncthreads();
    if (threadIdx.x == 0) {
        float S = 0.f, Q = 0.f;
        for (int w = 0; w < 4; ++w) { S += ls[w]; Q += lq[w]; }
        atomicAdd(&ssum[c], S); atomicAdd(&ssq[c], Q);
    }
}

// ---- BN2 stats from int16 conv sums: val = relu(alpha1[o]*k1[pix]*acc) ------------
__global__ void k_stats2(const short* __restrict__ ci, const float* __restrict__ alpha1,
                         const float* __restrict__ k1, float* __restrict__ ssum, float* __restrict__ ssq) {
    int plane = blockIdx.x;               // n*CC + o
    int o = plane & (CC - 1);
    int n = plane >> 8;
    const short* cp = ci + (size_t)plane * PP;
    const float* kp = k1 + (size_t)n * PP;
    float al = alpha1[o];
    float s = 0.f, q = 0.f;
    for (int i = threadIdx.x; i < PP; i += blockDim.x) {
        float v = fmaxf(al * kp[i] * (float)cp[i], 0.f);
        s += v; q = fmaf(v, v, q);
    }
#pragma unroll
    for (int off = 32; off; off >>= 1) { s += __shfl_down(s, off); q += __shfl_down(q, off); }
    __shared__ float ls[4], lq[4];
    int wv = threadIdx.x >> 6, ln = threadIdx.x & 63;
    if (ln == 0) { ls[wv] = s; lq[wv] = q; }
    __syncthreads();
    if (threadIdx.x == 0) {
        float S = 0.f, Q = 0.f;
        for (int w = 0; w < 4; ++w) { S += ls[w]; Q += lq[w]; }
        atomicAdd(&ssum[o], S); atomicAdd(&ssq[o], Q);
    }
}

// ---------------- finalize BN: scale = g/sqrt(var+eps), bias = beta - m*scale ------
__global__ void k_fin(const float* __restrict__ ssum, const float* __restrict__ ssq,
                      const float* __restrict__ gamma, const float* __restrict__ beta,
                      float* __restrict__ scale, float* __restrict__ bias) {
    int c = threadIdx.x;
    float m   = ssum[c] * (1.0f / NPIX);
    float var = fmaf(-m, m, ssq[c] * (1.0f / NPIX));
    float s   = gamma[c] / sqrtf(var + KEPS);
    scale[c] = s;
    bias[c]  = fmaf(-m, s, beta[c]);
}

// ---------------- weight prep: sign-pack + alpha + border-adjust table -------------
// adj[o][type] = 256*nvalid(type) + 2 * sum_{t in invalid(type)} popc(wbits[o][t])
// so conv can use zero-halo LDS and compute acc = adj - 2*P with NO per-tap selects.
__global__ void k_wprep(const float* __restrict__ w1, const float* __restrict__ w2,
                        uint32_t* __restrict__ wb1, uint32_t* __restrict__ wb2,
                        float* __restrict__ al1, float* __restrict__ al2,
                        int* __restrict__ adj1, int* __restrict__ adj2) {
    int o2 = blockIdx.x;                  // 0..511
    const float* w = (o2 < CC) ? w1 : w2;
    uint32_t* wb   = (o2 < CC) ? wb1 : wb2;
    float* al      = (o2 < CC) ? al1 : al2;
    int* adj       = (o2 < CC) ? adj1 : adj2;
    int o = o2 & (CC - 1);
    int lane = threadIdx.x;               // 64
    float asum = 0.f;
    int pt[9] = {0,0,0,0,0,0,0,0,0};      // popcount of sign bits per tap (all lanes)
    for (int cg = 0; cg < 4; ++cg) {
        int c = cg * 64 + lane;
        const float* wp = w + ((size_t)o * CC + c) * 9;
        for (int t = 0; t < 9; ++t) {
            float wv = wp[t];
            asum += fabsf(wv);
            unsigned long long m = __ballot(wv >= 0.0f);
            pt[t] += __popcll(m);
            if (lane == 0) {
                wb[(o * 9 + t) * W32 + cg * 2]     = (uint32_t)m;
                wb[(o * 9 + t) * W32 + cg * 2 + 1] = (uint32_t)(m >> 32);
            }
        }
    }
#pragma unroll
    for (int off = 32; off; off >>= 1) asum += __shfl_down(asum, off);
    if (lane == 0) al[o] = asum * (1.0f / 2304.0f);
    if (lane < 9) {
        const unsigned vm[3] = {0u, 0x007u, 0x1C0u};   // top rows / bottom rows
        const unsigned hm[3] = {0u, 0x049u, 0x124u};   // left cols / right cols
        unsigned mask = vm[lane / 3] | hm[lane % 3];
        int nv = 9 - __popc(mask);
        int wsum = 0;
#pragma unroll
        for (int t = 0; t < 9; ++t) if ((mask >> t) & 1) wsum += pt[t];
        adj[o * 16 + lane] = 256 * nv + 2 * wsum;
    }
}

// ---------------- BN1 apply + sign pack + channel-mean a1 --------------------------
__global__ void k_bn1pack(const float* __restrict__ x, const float* __restrict__ scale,
                          const float* __restrict__ bias, uint32_t* __restrict__ xbits,
                          float* __restrict__ a) {
    int lane = threadIdx.x & 63, wv = threadIdx.x >> 6;
    int n = blockIdx.x / 49;                        // 3136 = 49*64 pixels per image
    int pix = blockIdx.x * 64 + lane;
    int p = pix - n * PP;
    const float* xp = x + (size_t)n * CC * PP + p;
    uint32_t b0 = 0, b1 = 0;
    float asum = 0.f;
#pragma unroll
    for (int i = 0; i < 64; ++i) {
        int c = (wv << 6) + i;
        float v = xp[(size_t)c * PP];
        float bnv = fmaf(v, scale[c], bias[c]);
        asum += bnv;
        uint32_t bit = (bnv >= 0.0f) ? 1u : 0u;
        if (i < 32) b0 |= bit << i; else b1 |= bit << (i - 32);
    }
    ((uint2*)xbits)[(size_t)pix * 4 + wv] = make_uint2(b0, b1);
    __shared__ float lsum[4][64];
    lsum[wv][lane] = asum;
    __syncthreads();
    if (wv == 0)
        a[pix] = (lsum[0][lane] + lsum[1][lane] + lsum[2][lane] + lsum[3][lane]) * (1.0f / CC);
}

// ---------------- BN2 apply (recompute val from int16 conv) + pack + a2 ------------
__global__ void k_bn2pack(const short* __restrict__ ci, const float* __restrict__ alpha1,
                          const float* __restrict__ k1, const float* __restrict__ scale,
                          const float* __restrict__ bias, uint32_t* __restrict__ xbits,
                          float* __restrict__ a) {
    int lane = threadIdx.x & 63, wv = threadIdx.x >> 6;
    int n = blockIdx.x / 49;
    int pix = blockIdx.x * 64 + lane;
    int p = pix - n * PP;
    const short* cp = ci + (size_t)n * CC * PP + p;
    float kv = k1[pix];
    uint32_t b0 = 0, b1 = 0;
    float asum = 0.f;
#pragma unroll
    for (int i = 0; i < 64; ++i) {
        int o = (wv << 6) + i;
        float val = fmaxf(alpha1[o] * kv * (float)cp[(size_t)o * PP], 0.f);
        float bnv = fmaf(val, scale[o], bias[o]);
        asum += bnv;
        uint32_t bit = (bnv >= 0.0f) ? 1u : 0u;
        if (i < 32) b0 |= bit << i; else b1 |= bit << (i - 32);
    }
    ((uint2*)xbits)[(size_t)pix * 4 + wv] = make_uint2(b0, b1);
    __shared__ float lsum[4][64];
    lsum[wv][lane] = asum;
    __syncthreads();
    if (wv == 0)
        a[pix] = (lsum[0][lane] + lsum[1][lane] + lsum[2][lane] + lsum[3][lane]) * (1.0f / CC);
}

// ---------------- 3x3 box filter (zero padded, /9) ---------------------------------
__global__ void k_box(const float* __restrict__ a, float* __restrict__ k) {
    int gid = blockIdx.x * 256 + threadIdx.x;    // NPIX
    int n = gid / PP;
    int p = gid - n * PP;
    int h = p / WW, w = p - (p / WW) * WW;
    const float* ap = a + (size_t)n * PP;
    float s = 0.f;
    for (int dr = -1; dr <= 1; ++dr) {
        int hh = h + dr;
        if (hh < 0 || hh >= HH) continue;
        for (int dc = -1; dc <= 1; ++dc) {
            int ww2 = w + dc;
            if (ww2 < 0 || ww2 >= WW) continue;
            s += ap[hh * WW + ww2];
        }
    }
    k[gid] = s * (1.0f / 9.0f);
}

// ---------------- binary conv core: zero-halo xor+popcount -------------------------
// block: 448 threads = 8 rows x 56 cols, fixed n, TO=64 output channels.
// LDS x-tile has explicit zero halo on all sides -> inner loop is pure xor/popcount;
// border correction folded into adj[o][type] (acc = adj - 2*P).
template<bool FIRST>
__global__ __launch_bounds__(448, 4) void k_conv(
    const uint32_t* __restrict__ xbits, const uint32_t* __restrict__ wbits,
    const int* __restrict__ adj, const float* __restrict__ alpha,
    const float* __restrict__ kmap, short* __restrict__ out_i16,
    const float* __restrict__ ident, float* __restrict__ outf)
{
    constexpr int TH = 8, TO = 64;
    constexpr int LW = 58;                            // 56 + 2 col halo
    __shared__ uint32_t lds_x[(TH + 2) * LW * W32];   // 10*58*8*4 = 18560 B

    int b = blockIdx.x;
    int ob = b & 3, hb = (b >> 2) % 7, n = b / 28;
    int h0 = hb * TH, o0 = ob * TO;
    int tid = threadIdx.x;

    // stage rows h0-1..h0+TH, cols -1..56; zero outside image
    for (int i = tid; i < (TH + 2) * LW * 2; i += 448) {   // uint4 units, 116/row
        int r = i / (LW * 2), j = i - r * (LW * 2);
        int c = j >> 1, half = j & 1;
        int gr = h0 - 1 + r, gc = c - 1;
        uint4 v = make_uint4(0u, 0u, 0u, 0u);
        if (gr >= 0 && gr < HH && gc >= 0 && gc < WW)
            v = ((const uint4*)(xbits + ((size_t)n * PP + (size_t)gr * WW + gc) * W32))[half];
        ((uint4*)lds_x)[i] = v;
    }
    __syncthreads();

    int row = tid / WW, col = tid - (tid / WW) * WW;
    int h = h0 + row;
    int vf = (h == 0) ? 1 : ((h == HH - 1) ? 2 : 0);
    int hf = (col == 0) ? 1 : ((col == WW - 1) ? 2 : 0);
    int type = vf * 3 + hf;
    size_t gp = (size_t)n * PP + (size_t)h * WW + col;
    float kv = FIRST ? 0.f : kmap[gp];
    size_t obase = (size_t)n * CC * PP + (size_t)h * WW + col;

    // pull this pixel's 3x3 window (incl. zero halo) into registers: 72 u32
    uint32_t xw[9][W32];
#pragma unroll
    for (int t = 0; t < 9; ++t) {
        int base = ((row + t / 3) * LW + (col + t % 3)) * W32;
#pragma unroll
        for (int wd = 0; wd < W32; ++wd) xw[t][wd] = lds_x[base + wd];
    }

#pragma unroll 2
    for (int oi = 0; oi < TO; ++oi) {
        int o = o0 + oi;
        const uint4* __restrict__ wq = (const uint4*)(wbits + (size_t)o * 72);  // uniform
        int P = 0;
#pragma unroll
        for (int t = 0; t < 9; ++t) {
            uint4 wa = wq[2 * t], wb2 = wq[2 * t + 1];
            P += __popc(xw[t][0] ^ wa.x);
            P += __popc(xw[t][1] ^ wa.y);
            P += __popc(xw[t][2] ^ wa.z);
            P += __popc(xw[t][3] ^ wa.w);
            P += __popc(xw[t][4] ^ wb2.x);
            P += __popc(xw[t][5] ^ wb2.y);
            P += __popc(xw[t][6] ^ wb2.z);
            P += __popc(xw[t][7] ^ wb2.w);
        }
        int acc = adj[o * 16 + type] - 2 * P;
        size_t oidx = obase + (size_t)o * PP;
        if (FIRST) {
            out_i16[oidx] = (short)acc;
        } else {
            float res = alpha[o] * kv * (float)acc;
            outf[oidx] = fmaxf(res + ident[oidx], 0.f);
        }
    }
}

extern "C" void kernel_launch(void* const* d_in, const int* in_sizes, int n_in,
                              void* d_out, int out_size, void* d_ws, size_t ws_size,
                              hipStream_t stream)
{
    const float* x  = (const float*)d_in[0];
    const float* g1 = (const float*)d_in[1];
    const float* b1 = (const float*)d_in[2];
    const float* w1 = (const float*)d_in[3];
    const float* g2 = (const float*)d_in[4];
    const float* b2 = (const float*)d_in[5];
    const float* w2 = (const float*)d_in[6];
    float* out = (float*)d_out;

    char* ws = (char*)d_ws;
    float* s1sum  = (float*)(ws + 0);
    float* s1sq   = (float*)(ws + 1024);
    float* s2sum  = (float*)(ws + 2048);
    float* s2sq   = (float*)(ws + 3072);
    float* scale1 = (float*)(ws + 4096);
    float* bias1  = (float*)(ws + 5120);
    float* scale2 = (float*)(ws + 6144);
    float* bias2  = (float*)(ws + 7168);
    float* alpha1 = (float*)(ws + 8192);
    float* alpha2 = (float*)(ws + 9216);
    int*   adj1   = (int*)(ws + 10240);                   // 16384 B
    int*   adj2   = (int*)(ws + 26624);                   // 16384 B
    uint32_t* wbits1 = (uint32_t*)(ws + 43008);           // 73728 B
    uint32_t* wbits2 = (uint32_t*)(ws + 116736);          // 73728 B
    float* a1 = (float*)(ws + 190464);                    // 401408 B
    float* k1 = (float*)(ws + 591872);
    float* a2 = (float*)(ws + 993280);
    float* k2 = (float*)(ws + 1394688);
    uint32_t* xbits1 = (uint32_t*)(ws + 1796096);         // 3211264 B
    uint32_t* xbits2 = (uint32_t*)(ws + 5007360);         // 3211264 B
    short* ci = (short*)(ws + 8218624);                   // 51380224 B

    hipMemsetAsync(ws, 0, 4096, stream);                  // zero stat accumulators
    k_wprep<<<2 * CC, 64, 0, stream>>>(w1, w2, wbits1, wbits2, alpha1, alpha2, adj1, adj2);
    k_stats<<<NB * CC, 256, 0, stream>>>(x, s1sum, s1sq);
    k_fin<<<1, 256, 0, stream>>>(s1sum, s1sq, g1, b1, scale1, bias1);
    k_bn1pack<<<NPIX / 64, 256, 0, stream>>>(x, scale1, bias1, xbits1, a1);
    k_box<<<NPIX / 256, 256, 0, stream>>>(a1, k1);
    k_conv<true><<<NB * 7 * 4, 448, 0, stream>>>(xbits1, wbits1, adj1, nullptr, nullptr, ci, nullptr, nullptr);
    k_stats2<<<NB * CC, 256, 0, stream>>>(ci, alpha1, k1, s2sum, s2sq);
    k_fin<<<1, 256, 0, stream>>>(s2sum, s2sq, g2, b2, scale2, bias2);
    k_bn2pack<<<NPIX / 64, 256, 0, stream>>>(ci, alpha1, k1, scale2, bias2, xbits2, a2);
    k_box<<<NPIX / 256, 256, 0, stream>>>(a2, k2);
    k_conv<false><<<NB * 7 * 4, 448, 0, stream>>>(xbits2, wbits2, adj2, alpha2, k2, nullptr, x, out);
}

// Round 4
// 709.086 us; speedup vs baseline: 5.1366x; 5.1366x over previous
//
#include <hip/hip_runtime.h>
#include <stdint.h>

#define NB 32
#define CC 256
#define HH 56
#define WW 56
#define PP (HH*WW)          // 3136
#define NPIX (NB*PP)        // 100352
#define W32 8               // 256 channels / 32 bits
#define KEPS 1e-5f

// ---------------- BN stats: per-(n,c) plane partial sums -> atomics ----------------
__global__ void k_stats(const float* __restrict__ x, float* __restrict__ ssum, float* __restrict__ ssq) {
    int plane = blockIdx.x;               // n*CC + c
    int c = plane & (CC - 1);
    const float* xp = x + (size_t)plane * PP;
    float s = 0.f, q = 0.f;
    for (int i = threadIdx.x; i < PP; i += blockDim.x) {
        float v = xp[i]; s += v; q = fmaf(v, v, q);
    }
#pragma unroll
    for (int off = 32; off; off >>= 1) { s += __shfl_down(s, off); q += __shfl_down(q, off); }
    __shared__ float ls[4], lq[4];
    int wv = threadIdx.x >> 6, ln = threadIdx.x & 63;
    if (ln == 0) { ls[wv] = s; lq[wv] = q; }
    __syncthreads();
    if (threadIdx.x == 0) {
        float S = 0.f, Q = 0.f;
        for (int w = 0; w < 4; ++w) { S += ls[w]; Q += lq[w]; }
        atomicAdd(&ssum[c], S); atomicAdd(&ssq[c], Q);
    }
}

// ---- BN2 stats from int16 conv sums: val = relu(alpha1[o]*k1[pix]*acc) ------------
__global__ void k_stats2(const short* __restrict__ ci, const float* __restrict__ alpha1,
                         const float* __restrict__ k1, float* __restrict__ ssum, float* __restrict__ ssq) {
    int plane = blockIdx.x;               // n*CC + o
    int o = plane & (CC - 1);
    int n = plane >> 8;
    const short* cp = ci + (size_t)plane * PP;
    const float* kp = k1 + (size_t)n * PP;
    float al = alpha1[o];
    float s = 0.f, q = 0.f;
    for (int i = threadIdx.x; i < PP; i += blockDim.x) {
        float v = fmaxf(al * kp[i] * (float)cp[i], 0.f);
        s += v; q = fmaf(v, v, q);
    }
#pragma unroll
    for (int off = 32; off; off >>= 1) { s += __shfl_down(s, off); q += __shfl_down(q, off); }
    __shared__ float ls[4], lq[4];
    int wv = threadIdx.x >> 6, ln = threadIdx.x & 63;
    if (ln == 0) { ls[wv] = s; lq[wv] = q; }
    __syncthreads();
    if (threadIdx.x == 0) {
        float S = 0.f, Q = 0.f;
        for (int w = 0; w < 4; ++w) { S += ls[w]; Q += lq[w]; }
        atomicAdd(&ssum[o], S); atomicAdd(&ssq[o], Q);
    }
}

// ---------------- finalize BN: scale = g/sqrt(var+eps), bias = beta - m*scale ------
__global__ void k_fin(const float* __restrict__ ssum, const float* __restrict__ ssq,
                      const float* __restrict__ gamma, const float* __restrict__ beta,
                      float* __restrict__ scale, float* __restrict__ bias) {
    int c = threadIdx.x;
    float m   = ssum[c] * (1.0f / NPIX);
    float var = fmaf(-m, m, ssq[c] * (1.0f / NPIX));
    float s   = gamma[c] / sqrtf(var + KEPS);
    scale[c] = s;
    bias[c]  = fmaf(-m, s, beta[c]);
}

// ---------------- weight prep: sign-pack + alpha + border-adjust table -------------
// adj[o][type] = 256*nvalid(type) + 2 * sum_{t in invalid(type)} popc(wbits[o][t])
// so conv can use zero-halo LDS and compute acc = adj - 2*P with NO per-tap selects.
__global__ void k_wprep(const float* __restrict__ w1, const float* __restrict__ w2,
                        uint32_t* __restrict__ wb1, uint32_t* __restrict__ wb2,
                        float* __restrict__ al1, float* __restrict__ al2,
                        int* __restrict__ adj1, int* __restrict__ adj2) {
    int o2 = blockIdx.x;                  // 0..511
    const float* w = (o2 < CC) ? w1 : w2;
    uint32_t* wb   = (o2 < CC) ? wb1 : wb2;
    float* al      = (o2 < CC) ? al1 : al2;
    int* adj       = (o2 < CC) ? adj1 : adj2;
    int o = o2 & (CC - 1);
    int lane = threadIdx.x;               // 64
    float asum = 0.f;
    int pt[9] = {0,0,0,0,0,0,0,0,0};      // popcount of sign bits per tap (all lanes)
    for (int cg = 0; cg < 4; ++cg) {
        int c = cg * 64 + lane;
        const float* wp = w + ((size_t)o * CC + c) * 9;
        for (int t = 0; t < 9; ++t) {
            float wv = wp[t];
            asum += fabsf(wv);
            unsigned long long m = __ballot(wv >= 0.0f);
            pt[t] += __popcll(m);
            if (lane == 0) {
                wb[(o * 9 + t) * W32 + cg * 2]     = (uint32_t)m;
                wb[(o * 9 + t) * W32 + cg * 2 + 1] = (uint32_t)(m >> 32);
            }
        }
    }
#pragma unroll
    for (int off = 32; off; off >>= 1) asum += __shfl_down(asum, off);
    if (lane == 0) al[o] = asum * (1.0f / 2304.0f);
    if (lane < 9) {
        const unsigned vm[3] = {0u, 0x007u, 0x1C0u};   // top rows / bottom rows
        const unsigned hm[3] = {0u, 0x049u, 0x124u};   // left cols / right cols
        unsigned mask = vm[lane / 3] | hm[lane % 3];
        int nv = 9 - __popc(mask);
        int wsum = 0;
#pragma unroll
        for (int t = 0; t < 9; ++t) if ((mask >> t) & 1) wsum += pt[t];
        adj[o * 16 + lane] = 256 * nv + 2 * wsum;
    }
}

// ---------------- BN1 apply + sign pack + channel-mean a1 --------------------------
__global__ void k_bn1pack(const float* __restrict__ x, const float* __restrict__ scale,
                          const float* __restrict__ bias, uint32_t* __restrict__ xbits,
                          float* __restrict__ a) {
    int lane = threadIdx.x & 63, wv = threadIdx.x >> 6;
    int n = blockIdx.x / 49;                        // 3136 = 49*64 pixels per image
    int pix = blockIdx.x * 64 + lane;
    int p = pix - n * PP;
    const float* xp = x + (size_t)n * CC * PP + p;
    uint32_t b0 = 0, b1 = 0;
    float asum = 0.f;
#pragma unroll
    for (int i = 0; i < 64; ++i) {
        int c = (wv << 6) + i;
        float v = xp[(size_t)c * PP];
        float bnv = fmaf(v, scale[c], bias[c]);
        asum += bnv;
        uint32_t bit = (bnv >= 0.0f) ? 1u : 0u;
        if (i < 32) b0 |= bit << i; else b1 |= bit << (i - 32);
    }
    ((uint2*)xbits)[(size_t)pix * 4 + wv] = make_uint2(b0, b1);
    __shared__ float lsum[4][64];
    lsum[wv][lane] = asum;
    __syncthreads();
    if (wv == 0)
        a[pix] = (lsum[0][lane] + lsum[1][lane] + lsum[2][lane] + lsum[3][lane]) * (1.0f / CC);
}

// ---------------- BN2 apply (recompute val from int16 conv) + pack + a2 ------------
__global__ void k_bn2pack(const short* __restrict__ ci, const float* __restrict__ alpha1,
                          const float* __restrict__ k1, const float* __restrict__ scale,
                          const float* __restrict__ bias, uint32_t* __restrict__ xbits,
                          float* __restrict__ a) {
    int lane = threadIdx.x & 63, wv = threadIdx.x >> 6;
    int n = blockIdx.x / 49;
    int pix = blockIdx.x * 64 + lane;
    int p = pix - n * PP;
    const short* cp = ci + (size_t)n * CC * PP + p;
    float kv = k1[pix];
    uint32_t b0 = 0, b1 = 0;
    float asum = 0.f;
#pragma unroll
    for (int i = 0; i < 64; ++i) {
        int o = (wv << 6) + i;
        float val = fmaxf(alpha1[o] * kv * (float)cp[(size_t)o * PP], 0.f);
        float bnv = fmaf(val, scale[o], bias[o]);
        asum += bnv;
        uint32_t bit = (bnv >= 0.0f) ? 1u : 0u;
        if (i < 32) b0 |= bit << i; else b1 |= bit << (i - 32);
    }
    ((uint2*)xbits)[(size_t)pix * 4 + wv] = make_uint2(b0, b1);
    __shared__ float lsum[4][64];
    lsum[wv][lane] = asum;
    __syncthreads();
    if (wv == 0)
        a[pix] = (lsum[0][lane] + lsum[1][lane] + lsum[2][lane] + lsum[3][lane]) * (1.0f / CC);
}

// ---------------- 3x3 box filter (zero padded, /9) ---------------------------------
__global__ void k_box(const float* __restrict__ a, float* __restrict__ k) {
    int gid = blockIdx.x * 256 + threadIdx.x;    // NPIX
    int n = gid / PP;
    int p = gid - n * PP;
    int h = p / WW, w = p - (p / WW) * WW;
    const float* ap = a + (size_t)n * PP;
    float s = 0.f;
    for (int dr = -1; dr <= 1; ++dr) {
        int hh = h + dr;
        if (hh < 0 || hh >= HH) continue;
        for (int dc = -1; dc <= 1; ++dc) {
            int ww2 = w + dc;
            if (ww2 < 0 || ww2 >= WW) continue;
            s += ap[hh * WW + ww2];
        }
    }
    k[gid] = s * (1.0f / 9.0f);
}

// ---------------- binary conv core: zero-halo xor+popcount -------------------------
// block: 448 threads = 8 rows x 56 cols, fixed n, TO=64 output channels.
// The 72-word per-pixel window is PINNED in VGPRs via empty asm (prevents the
// allocator from re-materializing LDS reads inside the oi loop — the round-1/2
// hidden bottleneck). launch_bounds(448,1) lifts the VGPR cap (round 3's (448,4)
// capped at 64 VGPRs -> scratch spill catastrophe).
template<bool FIRST>
__global__ __launch_bounds__(448, 1) void k_conv(
    const uint32_t* __restrict__ xbits, const uint32_t* __restrict__ wbits,
    const int* __restrict__ adj, const float* __restrict__ alpha,
    const float* __restrict__ kmap, short* __restrict__ out_i16,
    const float* __restrict__ ident, float* __restrict__ outf)
{
    constexpr int TH = 8, TO = 64;
    constexpr int LW = 58;                            // 56 + 2 col halo
    __shared__ uint32_t lds_x[(TH + 2) * LW * W32];   // 10*58*8*4 = 18560 B

    int b = blockIdx.x;
    int ob = b & 3, hb = (b >> 2) % 7, n = b / 28;
    int h0 = hb * TH, o0 = ob * TO;
    int tid = threadIdx.x;

    // stage rows h0-1..h0+TH, cols -1..56; zero outside image
    for (int i = tid; i < (TH + 2) * LW * 2; i += 448) {   // uint4 units, 116/row
        int r = i / (LW * 2), j = i - r * (LW * 2);
        int c = j >> 1, half = j & 1;
        int gr = h0 - 1 + r, gc = c - 1;
        uint4 v = make_uint4(0u, 0u, 0u, 0u);
        if (gr >= 0 && gr < HH && gc >= 0 && gc < WW)
            v = ((const uint4*)(xbits + ((size_t)n * PP + (size_t)gr * WW + gc) * W32))[half];
        ((uint4*)lds_x)[i] = v;
    }
    __syncthreads();

    int row = tid / WW, col = tid - (tid / WW) * WW;
    int h = h0 + row;
    int vf = (h == 0) ? 1 : ((h == HH - 1) ? 2 : 0);
    int hf = (col == 0) ? 1 : ((col == WW - 1) ? 2 : 0);
    int type = vf * 3 + hf;
    size_t gp = (size_t)n * PP + (size_t)h * WW + col;
    float kv = FIRST ? 0.f : kmap[gp];
    size_t obase = (size_t)n * CC * PP + (size_t)h * WW + col;

    // pull this pixel's 3x3 window (incl. zero halo) into registers: 72 u32
    uint32_t xw[9][W32];
#pragma unroll
    for (int t = 0; t < 9; ++t) {
        int base = ((row + t / 3) * LW + (col + t % 3)) * W32;
#pragma unroll
        for (int wd = 0; wd < W32; ++wd) xw[t][wd] = lds_x[base + wd];
    }
    // pin window in VGPRs: empty asm "may modify" each value, so the compiler
    // cannot legally re-load it from LDS inside the oi loop.
#pragma unroll
    for (int t = 0; t < 9; ++t)
#pragma unroll
        for (int wd = 0; wd < W32; ++wd)
            asm volatile("" : "+v"(xw[t][wd]));

#pragma unroll 2
    for (int oi = 0; oi < TO; ++oi) {
        int o = o0 + oi;
        const uint4* __restrict__ wq = (const uint4*)(wbits + (size_t)o * 72);  // uniform -> s_load
        int P = 0;
#pragma unroll
        for (int t = 0; t < 9; ++t) {
            uint4 wa = wq[2 * t], wb2 = wq[2 * t + 1];
            P += __popc(xw[t][0] ^ wa.x);
            P += __popc(xw[t][1] ^ wa.y);
            P += __popc(xw[t][2] ^ wa.z);
            P += __popc(xw[t][3] ^ wa.w);
            P += __popc(xw[t][4] ^ wb2.x);
            P += __popc(xw[t][5] ^ wb2.y);
            P += __popc(xw[t][6] ^ wb2.z);
            P += __popc(xw[t][7] ^ wb2.w);
        }
        int acc = adj[o * 16 + type] - 2 * P;
        size_t oidx = obase + (size_t)o * PP;
        if (FIRST) {
            out_i16[oidx] = (short)acc;
        } else {
            float res = alpha[o] * kv * (float)acc;
            outf[oidx] = fmaxf(res + ident[oidx], 0.f);
        }
    }
}

extern "C" void kernel_launch(void* const* d_in, const int* in_sizes, int n_in,
                              void* d_out, int out_size, void* d_ws, size_t ws_size,
                              hipStream_t stream)
{
    const float* x  = (const float*)d_in[0];
    const float* g1 = (const float*)d_in[1];
    const float* b1 = (const float*)d_in[2];
    const float* w1 = (const float*)d_in[3];
    const float* g2 = (const float*)d_in[4];
    const float* b2 = (const float*)d_in[5];
    const float* w2 = (const float*)d_in[6];
    float* out = (float*)d_out;

    char* ws = (char*)d_ws;
    float* s1sum  = (float*)(ws + 0);
    float* s1sq   = (float*)(ws + 1024);
    float* s2sum  = (float*)(ws + 2048);
    float* s2sq   = (float*)(ws + 3072);
    float* scale1 = (float*)(ws + 4096);
    float* bias1  = (float*)(ws + 5120);
    float* scale2 = (float*)(ws + 6144);
    float* bias2  = (float*)(ws + 7168);
    float* alpha1 = (float*)(ws + 8192);
    float* alpha2 = (float*)(ws + 9216);
    int*   adj1   = (int*)(ws + 10240);                   // 16384 B
    int*   adj2   = (int*)(ws + 26624);                   // 16384 B
    uint32_t* wbits1 = (uint32_t*)(ws + 43008);           // 73728 B
    uint32_t* wbits2 = (uint32_t*)(ws + 116736);          // 73728 B
    float* a1 = (float*)(ws + 190464);                    // 401408 B
    float* k1 = (float*)(ws + 591872);
    float* a2 = (float*)(ws + 993280);
    float* k2 = (float*)(ws + 1394688);
    uint32_t* xbits1 = (uint32_t*)(ws + 1796096);         // 3211264 B
    uint32_t* xbits2 = (uint32_t*)(ws + 5007360);         // 3211264 B
    short* ci = (short*)(ws + 8218624);                   // 51380224 B

    hipMemsetAsync(ws, 0, 4096, stream);                  // zero stat accumulators
    k_wprep<<<2 * CC, 64, 0, stream>>>(w1, w2, wbits1, wbits2, alpha1, alpha2, adj1, adj2);
    k_stats<<<NB * CC, 256, 0, stream>>>(x, s1sum, s1sq);
    k_fin<<<1, 256, 0, stream>>>(s1sum, s1sq, g1, b1, scale1, bias1);
    k_bn1pack<<<NPIX / 64, 256, 0, stream>>>(x, scale1, bias1, xbits1, a1);
    k_box<<<NPIX / 256, 256, 0, stream>>>(a1, k1);
    k_conv<true><<<NB * 7 * 4, 448, 0, stream>>>(xbits1, wbits1, adj1, nullptr, nullptr, ci, nullptr, nullptr);
    k_stats2<<<NB * CC, 256, 0, stream>>>(ci, alpha1, k1, s2sum, s2sq);
    k_fin<<<1, 256, 0, stream>>>(s2sum, s2sq, g2, b2, scale2, bias2);
    k_bn2pack<<<NPIX / 64, 256, 0, stream>>>(ci, alpha1, k1, scale2, bias2, xbits2, a2);
    k_box<<<NPIX / 256, 256, 0, stream>>>(a2, k2);
    k_conv<false><<<NB * 7 * 4, 448, 0, stream>>>(xbits2, wbits2, adj2, alpha2, k2, nullptr, x, out);
}

// Round 5
// 575.525 us; speedup vs baseline: 6.3286x; 1.2321x over previous
//
#include <hip/hip_runtime.h>
#include <stdint.h>

#define NB 32
#define CC 256
#define HH 56
#define WW 56
#define PP (HH*WW)          // 3136
#define NPIX (NB*PP)        // 100352
#define W32 8               // 256 channels / 32 bits
#define KEPS 1e-5f

// ---------------- BN stats: per-(n,c) plane partial sums -> atomics ----------------
__global__ void k_stats(const float* __restrict__ x, float* __restrict__ ssum, float* __restrict__ ssq) {
    int plane = blockIdx.x;               // n*CC + c
    int c = plane & (CC - 1);
    const float* xp = x + (size_t)plane * PP;
    float s = 0.f, q = 0.f;
    for (int i = threadIdx.x; i < PP; i += blockDim.x) {
        float v = xp[i]; s += v; q = fmaf(v, v, q);
    }
#pragma unroll
    for (int off = 32; off; off >>= 1) { s += __shfl_down(s, off); q += __shfl_down(q, off); }
    __shared__ float ls[4], lq[4];
    int wv = threadIdx.x >> 6, ln = threadIdx.x & 63;
    if (ln == 0) { ls[wv] = s; lq[wv] = q; }
    __syncthreads();
    if (threadIdx.x == 0) {
        float S = 0.f, Q = 0.f;
        for (int w = 0; w < 4; ++w) { S += ls[w]; Q += lq[w]; }
        atomicAdd(&ssum[c], S); atomicAdd(&ssq[c], Q);
    }
}

// ---- BN2 stats from int16 conv sums: val = relu(alpha1[o]*k1[pix]*acc) ------------
__global__ void k_stats2(const short* __restrict__ ci, const float* __restrict__ alpha1,
                         const float* __restrict__ k1, float* __restrict__ ssum, float* __restrict__ ssq) {
    int plane = blockIdx.x;               // n*CC + o
    int o = plane & (CC - 1);
    int n = plane >> 8;
    const short* cp = ci + (size_t)plane * PP;
    const float* kp = k1 + (size_t)n * PP;
    float al = alpha1[o];
    float s = 0.f, q = 0.f;
    for (int i = threadIdx.x; i < PP; i += blockDim.x) {
        float v = fmaxf(al * kp[i] * (float)cp[i], 0.f);
        s += v; q = fmaf(v, v, q);
    }
#pragma unroll
    for (int off = 32; off; off >>= 1) { s += __shfl_down(s, off); q += __shfl_down(q, off); }
    __shared__ float ls[4], lq[4];
    int wv = threadIdx.x >> 6, ln = threadIdx.x & 63;
    if (ln == 0) { ls[wv] = s; lq[wv] = q; }
    __syncthreads();
    if (threadIdx.x == 0) {
        float S = 0.f, Q = 0.f;
        for (int w = 0; w < 4; ++w) { S += ls[w]; Q += lq[w]; }
        atomicAdd(&ssum[o], S); atomicAdd(&ssq[o], Q);
    }
}

// ---------------- finalize BN: scale = g/sqrt(var+eps), bias = beta - m*scale ------
__global__ void k_fin(const float* __restrict__ ssum, const float* __restrict__ ssq,
                      const float* __restrict__ gamma, const float* __restrict__ beta,
                      float* __restrict__ scale, float* __restrict__ bias) {
    int c = threadIdx.x;
    float m   = ssum[c] * (1.0f / NPIX);
    float var = fmaf(-m, m, ssq[c] * (1.0f / NPIX));
    float s   = gamma[c] / sqrtf(var + KEPS);
    scale[c] = s;
    bias[c]  = fmaf(-m, s, beta[c]);
}

// ---------------- weight prep: sign-pack + alpha + border-adjust table -------------
// NEW layout: wb[(t*CC + o)*W32 + wd]  (tap-major) so the conv's per-tap o-stream
// is contiguous for scalar loads.
// adj[o][type] = 256*nvalid(type) + 2 * sum_{t in invalid(type)} popc(wbits[o][t])
__global__ void k_wprep(const float* __restrict__ w1, const float* __restrict__ w2,
                        uint32_t* __restrict__ wb1, uint32_t* __restrict__ wb2,
                        float* __restrict__ al1, float* __restrict__ al2,
                        int* __restrict__ adj1, int* __restrict__ adj2) {
    int o2 = blockIdx.x;                  // 0..511
    const float* w = (o2 < CC) ? w1 : w2;
    uint32_t* wb   = (o2 < CC) ? wb1 : wb2;
    float* al      = (o2 < CC) ? al1 : al2;
    int* adj       = (o2 < CC) ? adj1 : adj2;
    int o = o2 & (CC - 1);
    int lane = threadIdx.x;               // 64
    float asum = 0.f;
    int pt[9] = {0,0,0,0,0,0,0,0,0};      // popcount of sign bits per tap (all lanes)
    for (int cg = 0; cg < 4; ++cg) {
        int c = cg * 64 + lane;
        const float* wp = w + ((size_t)o * CC + c) * 9;
        for (int t = 0; t < 9; ++t) {
            float wv = wp[t];
            asum += fabsf(wv);
            unsigned long long m = __ballot(wv >= 0.0f);
            pt[t] += __popcll(m);
            if (lane == 0) {
                wb[(t * CC + o) * W32 + cg * 2]     = (uint32_t)m;
                wb[(t * CC + o) * W32 + cg * 2 + 1] = (uint32_t)(m >> 32);
            }
        }
    }
#pragma unroll
    for (int off = 32; off; off >>= 1) asum += __shfl_down(asum, off);
    if (lane == 0) al[o] = asum * (1.0f / 2304.0f);
    if (lane < 9) {
        const unsigned vm[3] = {0u, 0x007u, 0x1C0u};   // top rows / bottom rows
        const unsigned hm[3] = {0u, 0x049u, 0x124u};   // left cols / right cols
        unsigned mask = vm[lane / 3] | hm[lane % 3];
        int nv = 9 - __popc(mask);
        int wsum = 0;
#pragma unroll
        for (int t = 0; t < 9; ++t) if ((mask >> t) & 1) wsum += pt[t];
        adj[o * 16 + lane] = 256 * nv + 2 * wsum;
    }
}

// ---------------- BN1 apply + sign pack + channel-mean a1 --------------------------
__global__ void k_bn1pack(const float* __restrict__ x, const float* __restrict__ scale,
                          const float* __restrict__ bias, uint32_t* __restrict__ xbits,
                          float* __restrict__ a) {
    int lane = threadIdx.x & 63, wv = threadIdx.x >> 6;
    int n = blockIdx.x / 49;                        // 3136 = 49*64 pixels per image
    int pix = blockIdx.x * 64 + lane;
    int p = pix - n * PP;
    const float* xp = x + (size_t)n * CC * PP + p;
    uint32_t b0 = 0, b1 = 0;
    float asum = 0.f;
#pragma unroll
    for (int i = 0; i < 64; ++i) {
        int c = (wv << 6) + i;
        float v = xp[(size_t)c * PP];
        float bnv = fmaf(v, scale[c], bias[c]);
        asum += bnv;
        uint32_t bit = (bnv >= 0.0f) ? 1u : 0u;
        if (i < 32) b0 |= bit << i; else b1 |= bit << (i - 32);
    }
    ((uint2*)xbits)[(size_t)pix * 4 + wv] = make_uint2(b0, b1);
    __shared__ float lsum[4][64];
    lsum[wv][lane] = asum;
    __syncthreads();
    if (wv == 0)
        a[pix] = (lsum[0][lane] + lsum[1][lane] + lsum[2][lane] + lsum[3][lane]) * (1.0f / CC);
}

// ---------------- BN2 apply (recompute val from int16 conv) + pack + a2 ------------
__global__ void k_bn2pack(const short* __restrict__ ci, const float* __restrict__ alpha1,
                          const float* __restrict__ k1, const float* __restrict__ scale,
                          const float* __restrict__ bias, uint32_t* __restrict__ xbits,
                          float* __restrict__ a) {
    int lane = threadIdx.x & 63, wv = threadIdx.x >> 6;
    int n = blockIdx.x / 49;
    int pix = blockIdx.x * 64 + lane;
    int p = pix - n * PP;
    const short* cp = ci + (size_t)n * CC * PP + p;
    float kv = k1[pix];
    uint32_t b0 = 0, b1 = 0;
    float asum = 0.f;
#pragma unroll
    for (int i = 0; i < 64; ++i) {
        int o = (wv << 6) + i;
        float val = fmaxf(alpha1[o] * kv * (float)cp[(size_t)o * PP], 0.f);
        float bnv = fmaf(val, scale[o], bias[o]);
        asum += bnv;
        uint32_t bit = (bnv >= 0.0f) ? 1u : 0u;
        if (i < 32) b0 |= bit << i; else b1 |= bit << (i - 32);
    }
    ((uint2*)xbits)[(size_t)pix * 4 + wv] = make_uint2(b0, b1);
    __shared__ float lsum[4][64];
    lsum[wv][lane] = asum;
    __syncthreads();
    if (wv == 0)
        a[pix] = (lsum[0][lane] + lsum[1][lane] + lsum[2][lane] + lsum[3][lane]) * (1.0f / CC);
}

// ---------------- 3x3 box filter (zero padded, /9) ---------------------------------
__global__ void k_box(const float* __restrict__ a, float* __restrict__ k) {
    int gid = blockIdx.x * 256 + threadIdx.x;    // NPIX
    int n = gid / PP;
    int p = gid - n * PP;
    int h = p / WW, w = p - (p / WW) * WW;
    const float* ap = a + (size_t)n * PP;
    float s = 0.f;
    for (int dr = -1; dr <= 1; ++dr) {
        int hh = h + dr;
        if (hh < 0 || hh >= HH) continue;
        for (int dc = -1; dc <= 1; ++dc) {
            int ww2 = w + dc;
            if (ww2 < 0 || ww2 >= WW) continue;
            s += ap[hh * WW + ww2];
        }
    }
    k[gid] = s * (1.0f / 9.0f);
}

// ---------------- binary conv core: tap-major, P-accumulator array -----------------
// block: 448 threads = 8 rows x 56 cols of pixels, fixed n, TO=32 output channels.
// Per tap: lane reads its 8 x-words from LDS (2 x b128); weights stream through
// SGPRs (wave-uniform pointer, tap-major layout -> contiguous s_loads); 32
// independent bcnt chains accumulate into P[32]. Live set ~60-70 VGPRs -> high
// occupancy, no AGPR spill traffic (the round-2/4 killer).
template<bool FIRST>
__global__ __launch_bounds__(448) void k_conv(
    const uint32_t* __restrict__ xbits, const uint32_t* __restrict__ wbits,
    const int* __restrict__ adj, const float* __restrict__ alpha,
    const float* __restrict__ kmap, short* __restrict__ out_i16,
    const float* __restrict__ ident, float* __restrict__ outf)
{
    constexpr int TH = 8, TO = 32;
    constexpr int LW = 58;                            // 56 + 2 col halo
    __shared__ uint32_t lds_x[(TH + 2) * LW * W32];   // 10*58*8*4 = 18560 B

    int b = blockIdx.x;
    int ob = b & 7, hb = (b >> 3) % 7, n = b / 56;
    int h0 = hb * TH, o0 = ob * TO;
    int tid = threadIdx.x;

    // stage rows h0-1..h0+TH, cols -1..56; zero outside image
    for (int i = tid; i < (TH + 2) * LW * 2; i += 448) {   // uint4 units, 116/row
        int r = i / (LW * 2), j = i - r * (LW * 2);
        int c = j >> 1, half = j & 1;
        int gr = h0 - 1 + r, gc = c - 1;
        uint4 v = make_uint4(0u, 0u, 0u, 0u);
        if (gr >= 0 && gr < HH && gc >= 0 && gc < WW)
            v = ((const uint4*)(xbits + ((size_t)n * PP + (size_t)gr * WW + gc) * W32))[half];
        ((uint4*)lds_x)[i] = v;
    }
    __syncthreads();

    int row = tid / WW, col = tid - (tid / WW) * WW;
    int h = h0 + row;
    int vf = (h == 0) ? 1 : ((h == HH - 1) ? 2 : 0);
    int hf = (col == 0) ? 1 : ((col == WW - 1) ? 2 : 0);
    int type = vf * 3 + hf;
    size_t gp = (size_t)n * PP + (size_t)h * WW + col;
    float kv = FIRST ? 0.f : kmap[gp];
    size_t obase = (size_t)n * CC * PP + (size_t)h * WW + col;

    int P[TO];
#pragma unroll
    for (int o = 0; o < TO; ++o) P[o] = 0;

    // tap loop kept rolled (9 iters): body ~550 instr = I-cache friendly
#pragma unroll 1
    for (int dr = 0; dr < 3; ++dr) {
#pragma unroll 1
        for (int dc = 0; dc < 3; ++dc) {
            int base = ((row + dr) * LW + (col + dc)) * W32;
            uint4 xa = *(const uint4*)&lds_x[base];
            uint4 xb = *(const uint4*)&lds_x[base + 4];
            int t = dr * 3 + dc;
            const uint4* __restrict__ wq = (const uint4*)wbits + ((size_t)t * CC + o0) * 2;
#pragma unroll
            for (int o = 0; o < TO; ++o) {
                uint4 wa = wq[o * 2], wb2 = wq[o * 2 + 1];
                int P0 = P[o];
                P0 += __popc(xa.x ^ wa.x);
                P0 += __popc(xa.y ^ wa.y);
                P0 += __popc(xa.z ^ wa.z);
                P0 += __popc(xa.w ^ wa.w);
                P0 += __popc(xb.x ^ wb2.x);
                P0 += __popc(xb.y ^ wb2.y);
                P0 += __popc(xb.z ^ wb2.z);
                P0 += __popc(xb.w ^ wb2.w);
                P[o] = P0;
            }
        }
    }

#pragma unroll
    for (int o = 0; o < TO; ++o) {
        int oo = o0 + o;
        int acc = adj[oo * 16 + type] - 2 * P[o];
        size_t oidx = obase + (size_t)oo * PP;
        if (FIRST) {
            out_i16[oidx] = (short)acc;
        } else {
            float res = alpha[oo] * kv * (float)acc;
            outf[oidx] = fmaxf(res + ident[oidx], 0.f);
        }
    }
}

extern "C" void kernel_launch(void* const* d_in, const int* in_sizes, int n_in,
                              void* d_out, int out_size, void* d_ws, size_t ws_size,
                              hipStream_t stream)
{
    const float* x  = (const float*)d_in[0];
    const float* g1 = (const float*)d_in[1];
    const float* b1 = (const float*)d_in[2];
    const float* w1 = (const float*)d_in[3];
    const float* g2 = (const float*)d_in[4];
    const float* b2 = (const float*)d_in[5];
    const float* w2 = (const float*)d_in[6];
    float* out = (float*)d_out;

    char* ws = (char*)d_ws;
    float* s1sum  = (float*)(ws + 0);
    float* s1sq   = (float*)(ws + 1024);
    float* s2sum  = (float*)(ws + 2048);
    float* s2sq   = (float*)(ws + 3072);
    float* scale1 = (float*)(ws + 4096);
    float* bias1  = (float*)(ws + 5120);
    float* scale2 = (float*)(ws + 6144);
    float* bias2  = (float*)(ws + 7168);
    float* alpha1 = (float*)(ws + 8192);
    float* alpha2 = (float*)(ws + 9216);
    int*   adj1   = (int*)(ws + 10240);                   // 16384 B
    int*   adj2   = (int*)(ws + 26624);                   // 16384 B
    uint32_t* wbits1 = (uint32_t*)(ws + 43008);           // 73728 B
    uint32_t* wbits2 = (uint32_t*)(ws + 116736);          // 73728 B
    float* a1 = (float*)(ws + 190464);                    // 401408 B
    float* k1 = (float*)(ws + 591872);
    float* a2 = (float*)(ws + 993280);
    float* k2 = (float*)(ws + 1394688);
    uint32_t* xbits1 = (uint32_t*)(ws + 1796096);         // 3211264 B
    uint32_t* xbits2 = (uint32_t*)(ws + 5007360);         // 3211264 B
    short* ci = (short*)(ws + 8218624);                   // 51380224 B

    hipMemsetAsync(ws, 0, 4096, stream);                  // zero stat accumulators
    k_wprep<<<2 * CC, 64, 0, stream>>>(w1, w2, wbits1, wbits2, alpha1, alpha2, adj1, adj2);
    k_stats<<<NB * CC, 256, 0, stream>>>(x, s1sum, s1sq);
    k_fin<<<1, 256, 0, stream>>>(s1sum, s1sq, g1, b1, scale1, bias1);
    k_bn1pack<<<NPIX / 64, 256, 0, stream>>>(x, scale1, bias1, xbits1, a1);
    k_box<<<NPIX / 256, 256, 0, stream>>>(a1, k1);
    k_conv<true><<<NB * 7 * 8, 448, 0, stream>>>(xbits1, wbits1, adj1, nullptr, nullptr, ci, nullptr, nullptr);
    k_stats2<<<NB * CC, 256, 0, stream>>>(ci, alpha1, k1, s2sum, s2sq);
    k_fin<<<1, 256, 0, stream>>>(s2sum, s2sq, g2, b2, scale2, bias2);
    k_bn2pack<<<NPIX / 64, 256, 0, stream>>>(ci, alpha1, k1, scale2, bias2, xbits2, a2);
    k_box<<<NPIX / 256, 256, 0, stream>>>(a2, k2);
    k_conv<false><<<NB * 7 * 8, 448, 0, stream>>>(xbits2, wbits2, adj2, alpha2, k2, nullptr, x, out);
}